// Round 5
// baseline (3149.176 us; speedup 1.0000x reference)
//
#include <hip/hip_runtime.h>
#include <stdint.h>
#include <math.h>

typedef unsigned long long u64;
typedef float nt_float4 __attribute__((ext_vector_type(4)));

#define NROW 12288
#define DFEAT 512
#define HDIM  1024
#define NB    96   // NROW/128

// ==================================================================================
// NUMERICS CONTRACT (validated round 9, absmax 1.95e-3):
//   - every GEMM C element = single-accumulator FMA chain, k ascending, in panels
//     (512) for K=512 and (512,512) for K=1024, panels merged with one f32 add.
//     K=1024 GEMMs are TWO K=512 launches: panel-A chain stored to f32 partial
//     buffer (exact round-trip), panel-B launch computes v = part + chainB — the
//     same single left-assoc add as round 9, then +bias (+resid);
//   - norm = numpy classic pairwise (unchanged);
//   - top-32: exact byte-radix select (same selected SET as u64-key pop loop);
//     0.5v+0.5v symmetric scatter unchanged.
// This round: 128x256 tiles with 8x16 acc/thread (halves LDS-read bytes per FMA —
// gemms are ds_read-throughput bound), triangle kept via paired 128-blocks,
// nontemporal zero_kernel (via clang ext_vector_type — HIP float4 rejected).
// Per-element FMA chains bit-identical to round 9.
// ==================================================================================

// ---------------- GEMM: 128x256 tile, 256 threads, 8x16/thread ----------
// MODE 0: C = relu(acc + bias)                (h1; K=512 full chain)
// MODE 2: C = acc                             (panel-A partial, raw)
// MODE 3: C = relu((part + acc) + bias)       (panel-B merge, h2)
// MODE 4: C = resid + ((part + acc) + bias)   (panel-B merge, feat)
template <int MODE>
__global__ __launch_bounds__(256, 2) void gemm256(
    const float* __restrict__ A, const float* __restrict__ B,
    const float* __restrict__ bias, const float* __restrict__ resid,
    const float* __restrict__ part, float* __restrict__ C,
    int Nn, int lda, int ldb)
{
  __shared__ float As[32][132];   // [k][m], +4 pad
  __shared__ float Bs[32][264];   // [k][n], +8 pad
  const int t = threadIdx.x;
  const int tn = t & 15, tm = t >> 4;
  const size_t m0 = (size_t)blockIdx.y * 128, n0 = (size_t)blockIdx.x * 256;

  float cur[2][4][4][4] = {};     // [ih][jh][i][j]

  for (int kt = 0; kt < 512; kt += 32) {
#pragma unroll
    for (int u = 0; u < 4; ++u) {
      int f = u * 256 + t, r = f >> 3, c = f & 7;
      float4 va = *(const float4*)(A + (m0 + r) * (size_t)lda + kt + 4 * c);
      As[4 * c + 0][r] = va.x; As[4 * c + 1][r] = va.y;
      As[4 * c + 2][r] = va.z; As[4 * c + 3][r] = va.w;
    }
#pragma unroll
    for (int u = 0; u < 8; ++u) {
      int f = u * 256 + t, r = f >> 3, c = f & 7;
      float4 vb = *(const float4*)(B + (n0 + r) * (size_t)ldb + kt + 4 * c);
      Bs[4 * c + 0][r] = vb.x; Bs[4 * c + 1][r] = vb.y;
      Bs[4 * c + 2][r] = vb.z; Bs[4 * c + 3][r] = vb.w;
    }
    __syncthreads();
#pragma unroll 2
    for (int kk = 0; kk < 32; ++kk) {
      float4 a0 = *(const float4*)&As[kk][4 * tm];
      float4 a1 = *(const float4*)&As[kk][64 + 4 * tm];
      float4 b0 = *(const float4*)&Bs[kk][4 * tn];
      float4 b1 = *(const float4*)&Bs[kk][64 + 4 * tn];
      float4 b2 = *(const float4*)&Bs[kk][128 + 4 * tn];
      float4 b3 = *(const float4*)&Bs[kk][192 + 4 * tn];
      float av[2][4] = {{a0.x, a0.y, a0.z, a0.w}, {a1.x, a1.y, a1.z, a1.w}};
      float bv[4][4] = {{b0.x, b0.y, b0.z, b0.w}, {b1.x, b1.y, b1.z, b1.w},
                        {b2.x, b2.y, b2.z, b2.w}, {b3.x, b3.y, b3.z, b3.w}};
#pragma unroll
      for (int ih = 0; ih < 2; ++ih)
#pragma unroll
        for (int jh = 0; jh < 4; ++jh)
#pragma unroll
          for (int i = 0; i < 4; ++i)
#pragma unroll
            for (int j = 0; j < 4; ++j)
              cur[ih][jh][i][j] = fmaf(av[ih][i], bv[jh][j], cur[ih][jh][i][j]);
    }
    __syncthreads();
  }

#pragma unroll
  for (int ih = 0; ih < 2; ++ih)
#pragma unroll
    for (int i = 0; i < 4; ++i) {
      size_t gm = m0 + 64 * ih + 4 * tm + i;
#pragma unroll
      for (int jh = 0; jh < 4; ++jh) {
        size_t gn = n0 + 64 * jh + 4 * tn;
        float pj[4] = {0.f, 0.f, 0.f, 0.f};
        if (MODE == 3 || MODE == 4) {
          float4 pv = *(const float4*)(part + gm * (size_t)Nn + gn);
          pj[0] = pv.x; pj[1] = pv.y; pj[2] = pv.z; pj[3] = pv.w;
        }
        float rj[4] = {0.f, 0.f, 0.f, 0.f};
        if (MODE == 4) {
          float4 rv4 = *(const float4*)(resid + gm * (size_t)Nn + gn);
          rj[0] = rv4.x; rj[1] = rv4.y; rj[2] = rv4.z; rj[3] = rv4.w;
        }
        float rv[4];
#pragma unroll
        for (int j = 0; j < 4; ++j) {
          float v = cur[ih][jh][i][j];
          if (MODE == 3 || MODE == 4) v = pj[j] + v;   // panel merge: one f32 add
          if (MODE != 2) v = v + bias[gn + j];
          if (MODE == 0 || MODE == 3) v = v > 0.f ? v : 0.f;
          if (MODE == 4) v = rj[j] + v;
          rv[j] = v;
        }
        float4 res = {rv[0], rv[1], rv[2], rv[3]};
        *(float4*)(C + gm * (size_t)Nn + gn) = res;
      }
    }
}

// ---------------- symmetric sim GEMM: 128x256 tiles over upper triangle ----------
// Tile (bi, J) covers 128-blocks (bi, 2J) and (bi, 2J+1); exists iff 2J+1 >= bi.
// bi == 2J+1: only the right (diagonal) half is written (left computed, discarded).
// Mirror (transpose) written for strictly-off-diagonal halves.
__global__ __launch_bounds__(256, 2) void gemmsym(
    const float* __restrict__ F, float* __restrict__ C)
{
  __shared__ float As[32][132];
  __shared__ float Bs[32][264];
  const int t = threadIdx.x;
  const int tn = t & 15, tm = t >> 4;
  const int J = blockIdx.x, bi = blockIdx.y;
  if (2 * J + 1 < bi) return;
  const size_t m0 = (size_t)bi * 128, n0 = (size_t)J * 256;

  float cur[2][4][4][4] = {};

  for (int kt = 0; kt < DFEAT; kt += 32) {
#pragma unroll
    for (int u = 0; u < 4; ++u) {
      int f = u * 256 + t, r = f >> 3, c = f & 7;
      float4 va = *(const float4*)(F + (m0 + r) * (size_t)DFEAT + kt + 4 * c);
      As[4 * c + 0][r] = va.x; As[4 * c + 1][r] = va.y;
      As[4 * c + 2][r] = va.z; As[4 * c + 3][r] = va.w;
    }
#pragma unroll
    for (int u = 0; u < 8; ++u) {
      int f = u * 256 + t, r = f >> 3, c = f & 7;
      float4 vb = *(const float4*)(F + (n0 + r) * (size_t)DFEAT + kt + 4 * c);
      Bs[4 * c + 0][r] = vb.x; Bs[4 * c + 1][r] = vb.y;
      Bs[4 * c + 2][r] = vb.z; Bs[4 * c + 3][r] = vb.w;
    }
    __syncthreads();
#pragma unroll 2
    for (int kk = 0; kk < 32; ++kk) {
      float4 a0 = *(const float4*)&As[kk][4 * tm];
      float4 a1 = *(const float4*)&As[kk][64 + 4 * tm];
      float4 b0 = *(const float4*)&Bs[kk][4 * tn];
      float4 b1 = *(const float4*)&Bs[kk][64 + 4 * tn];
      float4 b2 = *(const float4*)&Bs[kk][128 + 4 * tn];
      float4 b3 = *(const float4*)&Bs[kk][192 + 4 * tn];
      float av[2][4] = {{a0.x, a0.y, a0.z, a0.w}, {a1.x, a1.y, a1.z, a1.w}};
      float bv[4][4] = {{b0.x, b0.y, b0.z, b0.w}, {b1.x, b1.y, b1.z, b1.w},
                        {b2.x, b2.y, b2.z, b2.w}, {b3.x, b3.y, b3.z, b3.w}};
#pragma unroll
      for (int ih = 0; ih < 2; ++ih)
#pragma unroll
        for (int jh = 0; jh < 4; ++jh)
#pragma unroll
          for (int i = 0; i < 4; ++i)
#pragma unroll
            for (int j = 0; j < 4; ++j)
              cur[ih][jh][i][j] = fmaf(av[ih][i], bv[jh][j], cur[ih][jh][i][j]);
    }
    __syncthreads();
  }

  // relu in place
#pragma unroll
  for (int ih = 0; ih < 2; ++ih)
#pragma unroll
    for (int jh = 0; jh < 4; ++jh)
#pragma unroll
      for (int i = 0; i < 4; ++i)
#pragma unroll
        for (int j = 0; j < 4; ++j)
          cur[ih][jh][i][j] = cur[ih][jh][i][j] > 0.f ? cur[ih][jh][i][j] : 0.f;

  const bool wL = (2 * J >= bi);       // left half in upper triangle
  const bool mL = (2 * J > bi);        // left half strictly off-diagonal
  const bool mR = (2 * J + 1 > bi);    // right half strictly off-diagonal

  // normal tile write (coalesced)
#pragma unroll
  for (int ih = 0; ih < 2; ++ih)
#pragma unroll
    for (int i = 0; i < 4; ++i) {
      size_t gm = m0 + 64 * ih + 4 * tm + i;
#pragma unroll
      for (int jh = 0; jh < 4; ++jh) {
        if (jh < 2 && !wL) continue;
        float4 res = {cur[ih][jh][i][0], cur[ih][jh][i][1],
                      cur[ih][jh][i][2], cur[ih][jh][i][3]};
        *(float4*)(C + gm * (size_t)NROW + n0 + 64 * jh + 4 * tn) = res;
      }
    }
  // mirrored tile write
#pragma unroll
  for (int jh = 0; jh < 4; ++jh) {
    if (jh < 2 ? !mL : !mR) continue;
#pragma unroll
    for (int j = 0; j < 4; ++j) {
      size_t gn = n0 + 64 * jh + 4 * tn + j;
#pragma unroll
      for (int ih = 0; ih < 2; ++ih) {
        float4 res = {cur[ih][jh][0][j], cur[ih][jh][1][j],
                      cur[ih][jh][2][j], cur[ih][jh][3][j]};
        *(float4*)(C + gn * (size_t)NROW + m0 + 64 * ih + 4 * tm) = res;
      }
    }
  }
}

// ---------------- norm + fn: numpy classic pairwise (UNCHANGED, bit-critical) -----
__global__ __launch_bounds__(256) void norm_fn_kernel(const float* __restrict__ feat,
                                                      float* __restrict__ fn) {
#pragma clang fp contract(off)
  const int row = blockIdx.x * 4 + (threadIdx.x >> 6);
  const int lane = threadIdx.x & 63;
  const float* fr = feat + (size_t)row * DFEAT;
  float r = 0.f;
  if (lane < 32) {
    const float* bp = fr + (lane >> 3) * 128 + (lane & 7);
    float x = bp[0];
    r = x * x;
#pragma unroll
    for (int i = 8; i <= 120; i += 8) {
      float x2 = bp[i];
      float s = x2 * x2;
      r = r + s;
    }
  }
  float v[32];
#pragma unroll
  for (int j = 0; j < 32; ++j) v[j] = __shfl(r, j);
  float Bv[4];
#pragma unroll
  for (int b = 0; b < 4; ++b) {
    const float* p = v + 8 * b;
    Bv[b] = ((p[0] + p[1]) + (p[2] + p[3])) + ((p[4] + p[5]) + (p[6] + p[7]));
  }
  float S = (Bv[0] + Bv[1]) + (Bv[2] + Bv[3]);
  float den = (float)sqrt((double)S) + 1e-8f;
#pragma unroll
  for (int e = 0; e < 8; ++e) {
    int d = e * 64 + lane;
    fn[(size_t)row * DFEAT + d] = fr[d] / den;
  }
}

// ---------------- per-row top-32: exact byte-radix select (UNCHANGED) ----------
__device__ __forceinline__ void radix_scan(unsigned int* hist, int* st, int t) {
  if (t < 64) {
    int h0 = (int)hist[4 * t + 0], h1 = (int)hist[4 * t + 1],
        h2 = (int)hist[4 * t + 2], h3 = (int)hist[4 * t + 3];
    int S = h0 + h1 + h2 + h3;
#pragma unroll
    for (int off = 1; off < 64; off <<= 1) {
      int o = __shfl_down(S, off);
      if (t + off < 64) S += o;
    }
    int Sn = __shfl_down(S, 1);
    if (t == 63) Sn = 0;
    int needed = st[1];
    if (S >= needed && Sn < needed) {
      int cg = Sn, b;
      if (cg + h3 >= needed) b = 3;
      else if ((cg += h3) + h2 >= needed) b = 2;
      else if ((cg += h2) + h1 >= needed) b = 1;
      else { cg += h1; b = 0; }
      st[0] = (st[0] << 8) | (4 * t + b);
      st[1] = needed - cg;
    }
    if (t == 0 && S < needed) { st[2] = 1; st[1] = needed - S; }
  }
}

__global__ __launch_bounds__(256, 3) void topk_kernel(
    const float* __restrict__ sim, float* __restrict__ topv, int* __restrict__ topi)
{
  __shared__ __align__(16) unsigned int svb[NROW];  // 48 KiB: row value bits
  __shared__ unsigned int hist[256];
  __shared__ int st[4];
  __shared__ int smin[4];
  const int row = blockIdx.x, t = threadIdx.x;
  const float4* rp = (const float4*)(sim + (size_t)row * NROW);

  hist[t] = 0;
  if (t == 0) { st[0] = 0; st[1] = 32; st[2] = 0; st[3] = 0; }
  __syncthreads();

#pragma unroll
  for (int it = 0; it < 12; ++it) {
    int q = t + 256 * it;
    float4 v = rp[q];
    unsigned w0 = __float_as_uint(v.x), w1 = __float_as_uint(v.y),
             w2 = __float_as_uint(v.z), w3 = __float_as_uint(v.w);
    uint4 u; u.x = w0; u.y = w1; u.z = w2; u.w = w3;
    *(uint4*)&svb[4 * q] = u;
    if (w0) atomicAdd(&hist[w0 >> 24], 1u);
    if (w1) atomicAdd(&hist[w1 >> 24], 1u);
    if (w2) atomicAdd(&hist[w2 >> 24], 1u);
    if (w3) atomicAdd(&hist[w3 >> 24], 1u);
  }
  __syncthreads();
  radix_scan(hist, st, t);
  __syncthreads();

  for (int p = 1; p < 4; ++p) {
    if (st[2]) break;
    unsigned pref = (unsigned)st[0];
    const int sh = 24 - 8 * p;
    hist[t] = 0;
    __syncthreads();
#pragma unroll
    for (int it = 0; it < 12; ++it) {
      uint4 u = *(const uint4*)&svb[4 * (t + 256 * it)];
      unsigned ws[4] = {u.x, u.y, u.z, u.w};
#pragma unroll
      for (int e = 0; e < 4; ++e)
        if ((ws[e] >> (sh + 8)) == pref)
          atomicAdd(&hist[(ws[e] >> sh) & 255u], 1u);
    }
    __syncthreads();
    radix_scan(hist, st, t);
    __syncthreads();
  }

  const unsigned T = (unsigned)st[0];
  const int r = st[1];

#pragma unroll
  for (int it = 0; it < 12; ++it) {
    uint4 u = *(const uint4*)&svb[4 * (t + 256 * it)];
    unsigned ws[4] = {u.x, u.y, u.z, u.w};
#pragma unroll
    for (int e = 0; e < 4; ++e)
      if (ws[e] > T) {
        int pos = atomicAdd(&st[3], 1);
        topv[row * 32 + pos] = __uint_as_float(ws[e]);
        topi[row * 32 + pos] = 4 * (t + 256 * it) + e;
      }
  }

  int last = -1;
  const int base = 32 - r;
  for (int rd = 0; rd < r; ++rd) {
    int lm = 0x7fffffff;
#pragma unroll
    for (int it = 0; it < 12; ++it) {
      uint4 u = *(const uint4*)&svb[4 * (t + 256 * it)];
      unsigned ws[4] = {u.x, u.y, u.z, u.w};
#pragma unroll
      for (int e = 0; e < 4; ++e) {
        int j = 4 * (t + 256 * it) + e;
        if (ws[e] == T && j > last && j < lm) lm = j;
      }
    }
#pragma unroll
    for (int off = 32; off >= 1; off >>= 1) {
      int o = __shfl_xor(lm, off);
      if (o < lm) lm = o;
    }
    if ((t & 63) == 0) smin[t >> 6] = lm;
    __syncthreads();
    int g0 = smin[0] < smin[1] ? smin[0] : smin[1];
    int g1 = smin[2] < smin[3] ? smin[2] : smin[3];
    int g = g0 < g1 ? g0 : g1;
    if (t == 0) {
      topv[row * 32 + base + rd] = __uint_as_float(T);
      topi[row * 32 + base + rd] = g;
    }
    last = g;
    __syncthreads();
  }
}

// ---------------- zero (nontemporal: skip write-RFO fetch) + scatter ----------
__global__ __launch_bounds__(256) void zero_kernel(float* __restrict__ out) {
  size_t i = ((size_t)blockIdx.x * 256 + threadIdx.x) * 4;
  nt_float4 z = {0.f, 0.f, 0.f, 0.f};
  __builtin_nontemporal_store(z, (nt_float4*)(out + i));
}

__global__ __launch_bounds__(256) void scatter_kernel(
    const float* __restrict__ topv, const int* __restrict__ topi, float* __restrict__ out) {
  int g = blockIdx.x * 256 + threadIdx.x;
  int row = g >> 5;
  float v = 0.5f * topv[g];
  int j = topi[g];
  atomicAdd(out + (size_t)row * NROW + j, v);
  atomicAdd(out + (size_t)j * NROW + row, v);
}

// ---------------- launch ----------------
extern "C" void kernel_launch(void* const* d_in, const int* in_sizes, int n_in,
                              void* d_out, int out_size, void* d_ws, size_t ws_size,
                              hipStream_t stream)
{
  const float* X  = (const float*)d_in[0];
  const float* W1 = (const float*)d_in[1];
  const float* b1 = (const float*)d_in[2];
  const float* W2 = (const float*)d_in[3];
  const float* b2 = (const float*)d_in[4];
  const float* W3 = (const float*)d_in[5];
  const float* b3 = (const float*)d_in[6];
  float* out = (float*)d_out;

  char* ws = (char*)d_ws;
  size_t off = 0;
  auto carve = [&](size_t bytes) {
    char* p = ws + off;
    off += (bytes + 255) & ~(size_t)255;
    return (void*)p;
  };

  float* h1   = (float*)carve(4ull * NROW * HDIM);
  float* h2   = (float*)carve(4ull * NROW * HDIM);
  float* feat = (float*)carve(4ull * NROW * DFEAT);
  float* fn   = (float*)carve(4ull * NROW * DFEAT);
  float* topv = (float*)carve(4ull * NROW * 32);
  int*   topi = (int*)carve(4ull * NROW * 32);

  // Partial buffers alias currently-dead regions:
  //  P2 (12288x1024, 50MB) = feat+fn (contiguous carves, both free during MLP)
  //  P3 (12288x512, 25MB)  = fn
  float* P2 = feat;
  float* P3 = fn;

  // W1: K=512 single chain
  gemm256<0><<<dim3(HDIM / 256, NROW / 128), 256, 0, stream>>>(
      X, W1, b1, nullptr, nullptr, h1, HDIM, DFEAT, DFEAT);
  // W2: K=1024 as (512,512) panels merged with one add
  gemm256<2><<<dim3(HDIM / 256, NROW / 128), 256, 0, stream>>>(
      h1, W2, nullptr, nullptr, nullptr, P2, HDIM, HDIM, HDIM);
  gemm256<3><<<dim3(HDIM / 256, NROW / 128), 256, 0, stream>>>(
      h1 + 512, W2 + 512, b2, nullptr, P2, h2, HDIM, HDIM, HDIM);
  // W3: K=1024 as (512,512) panels, + resid
  gemm256<2><<<dim3(DFEAT / 256, NROW / 128), 256, 0, stream>>>(
      h2, W3, nullptr, nullptr, nullptr, P3, DFEAT, HDIM, HDIM);
  gemm256<4><<<dim3(DFEAT / 256, NROW / 128), 256, 0, stream>>>(
      h2 + 512, W3 + 512, b3, X, P3, feat, DFEAT, HDIM, HDIM);

  // norm + fn (overwrites P3 region — P3 dead by now)
  norm_fn_kernel<<<NROW / 4, 256, 0, stream>>>(feat, fn);

  // sim = relu(fn @ fn^T): 128x256 tiles over upper triangle (48 x 96 grid,
  // inactive tiles early-exit)
  gemmsym<<<dim3(48, 96), 256, 0, stream>>>(fn, out);

  // top-32 per row
  topk_kernel<<<NROW, 256, 0, stream>>>(out, topv, topi);

  // zero + symmetric scatter
  zero_kernel<<<(int)(((size_t)NROW * NROW / 4) / 256), 256, 0, stream>>>(out);
  scatter_kernel<<<(NROW * 32) / 256, 256, 0, stream>>>(topv, topi, out);
}

// Round 6
// 2833.058 us; speedup vs baseline: 1.1116x; 1.1116x over previous
//
#include <hip/hip_runtime.h>
#include <stdint.h>
#include <math.h>

typedef unsigned long long u64;
typedef float nt_float4 __attribute__((ext_vector_type(4)));

#define NROW 12288
#define DFEAT 512
#define HDIM  1024
#define NB    96   // NROW/128

// ==================================================================================
// NUMERICS CONTRACT (validated round 9, absmax 1.95e-3):
//   - every GEMM C element = single-accumulator FMA chain, k ascending, in panels
//     (512) for K=512 and (512,512) for K=1024, panels merged with one f32 add;
//   - norm = numpy classic pairwise (unchanged);
//   - top-32: exact byte-radix select (same selected SET as u64-key pop loop);
//     0.5v+0.5v symmetric scatter unchanged.
// Round 6: revert to round-3 proven 128x128/8x8 structure (round-5's 8x16 tile
// collapsed occupancy to 1 block/CU). Change: remove LDS padding — XOR swizzle
// already kills conflicts — so block LDS = 32768 B exactly -> 5 blocks/CU
// (160 KiB exactly), +56% resident waves. NT zero store kept.
// Per-element FMA chains bit-identical to round 9.
// ==================================================================================

// ---------------- MLP GEMM: 128x128 tile, 8x8/thread (2x2 groups of 4x4) ----------
// MODE 0: store relu(v + bias)      (h1, h2)
// MODE 1: store resid + (v + bias)  (feat = X + h)
// NPANEL: 1 -> K=512 single chain; 2 -> K=1024 chains (512,512) merged with one add.
template <int MODE, int NPANEL>
__global__ __launch_bounds__(256, 3) void gemm128(
    const float* __restrict__ A, const float* __restrict__ B,
    const float* __restrict__ bias, const float* __restrict__ resid,
    float* __restrict__ C, int Nn, int K)
{
  __shared__ float As[32][128];   // [k][m], XOR-swizzled m-groups, no pad
  __shared__ float Bs[32][128];   // [k][n]
  const int t = threadIdx.x;
  const int tn = t & 15, tm = t >> 4;
  const size_t m0 = (size_t)blockIdx.y * 128, n0 = (size_t)blockIdx.x * 128;

  float cur[2][2][4][4] = {};             // [ih][jh][i][j]
  float tot[2][2][4][4];                  // used only when NPANEL==2

  for (int kt = 0; kt < K; kt += 32) {
#pragma unroll
    for (int u = 0; u < 4; ++u) {
      int f = u * 256 + t;
      int r = f >> 3, c = f & 7;
      int pm = (r & 3) + 4 * ((r >> 2) ^ c);   // swizzled m-slot (bijective per k-row)
      float4 va = *(const float4*)(A + (m0 + r) * (size_t)K + kt + 4 * c);
      As[4 * c + 0][pm] = va.x; As[4 * c + 1][pm] = va.y;
      As[4 * c + 2][pm] = va.z; As[4 * c + 3][pm] = va.w;
      float4 vb = *(const float4*)(B + (n0 + r) * (size_t)K + kt + 4 * c);
      Bs[4 * c + 0][pm] = vb.x; Bs[4 * c + 1][pm] = vb.y;
      Bs[4 * c + 2][pm] = vb.z; Bs[4 * c + 3][pm] = vb.w;
    }
    __syncthreads();
#pragma unroll 4
    for (int kk = 0; kk < 32; ++kk) {
      const int key = kk >> 2;
      float4 a0 = *(const float4*)&As[kk][4 * (tm ^ key)];
      float4 a1 = *(const float4*)&As[kk][4 * (16 + (tm ^ key))];
      float4 b0 = *(const float4*)&Bs[kk][4 * (tn ^ key)];
      float4 b1 = *(const float4*)&Bs[kk][4 * (16 + (tn ^ key))];
      float av[2][4] = {{a0.x, a0.y, a0.z, a0.w}, {a1.x, a1.y, a1.z, a1.w}};
      float bv[2][4] = {{b0.x, b0.y, b0.z, b0.w}, {b1.x, b1.y, b1.z, b1.w}};
#pragma unroll
      for (int ih = 0; ih < 2; ++ih)
#pragma unroll
        for (int jh = 0; jh < 2; ++jh)
#pragma unroll
          for (int i = 0; i < 4; ++i)
#pragma unroll
            for (int j = 0; j < 4; ++j)
              cur[ih][jh][i][j] = fmaf(av[ih][i], bv[jh][j], cur[ih][jh][i][j]);
    }
    __syncthreads();
    if (NPANEL == 2) {
      int ke = kt + 32;
      if (ke == 512) {          // first panel ends: move, restart chain
#pragma unroll
        for (int ih = 0; ih < 2; ++ih)
#pragma unroll
          for (int jh = 0; jh < 2; ++jh)
#pragma unroll
            for (int i = 0; i < 4; ++i)
#pragma unroll
              for (int j = 0; j < 4; ++j) {
                tot[ih][jh][i][j] = cur[ih][jh][i][j];
                cur[ih][jh][i][j] = 0.f;
              }
      }
    }
  }
  // final value: NPANEL==1 -> cur; NPANEL==2 -> tot + cur (one add, left-assoc)
#pragma unroll
  for (int ih = 0; ih < 2; ++ih)
#pragma unroll
    for (int i = 0; i < 4; ++i) {
      size_t gm = m0 + 64 * ih + 4 * tm + i;
#pragma unroll
      for (int jh = 0; jh < 2; ++jh) {
        size_t gn = n0 + 64 * jh + 4 * tn;
        float rv[4];
#pragma unroll
        for (int j = 0; j < 4; ++j) {
          float v = (NPANEL == 2) ? (tot[ih][jh][i][j] + cur[ih][jh][i][j])
                                  : cur[ih][jh][i][j];
          v = v + bias[gn + j];
          if (MODE == 0) {
            v = v > 0.f ? v : 0.f;
          } else {
            v = resid[gm * (size_t)Nn + gn + j] + v;
          }
          rv[j] = v;
        }
        float4 res = {rv[0], rv[1], rv[2], rv[3]};
        *(float4*)(C + gm * (size_t)Nn + gn) = res;
      }
    }
}

// ---------------- symmetric sim GEMM: upper-tri blocks, write tile + mirror -------
// sim = relu(fn @ fn^T): s_ij bit-equals s_ji (commutative multiply, same chain),
// so compute bi<=bj only. K=512, single panel.
__global__ __launch_bounds__(256, 4) void gemmsym(
    const float* __restrict__ F, float* __restrict__ C)
{
  __shared__ float As[32][128];
  __shared__ float Bs[32][128];
  const int t = threadIdx.x;
  const int tn = t & 15, tm = t >> 4;

  // decode linear block -> (bi, bj), bi<=bj; S(b) = b*NB - b*(b-1)/2
  int lin = blockIdx.x;
  int bi = (int)(NB + 0.5 - sqrt((NB + 0.5) * (NB + 0.5) - 2.0 * (double)lin));
  if (bi < 0) bi = 0;
  if (bi > NB - 1) bi = NB - 1;
  while (bi + 1 <= NB - 1 && (bi + 1) * NB - ((bi + 1) * bi) / 2 <= lin) ++bi;
  while (bi * NB - (bi * (bi - 1)) / 2 > lin) --bi;
  int bj = bi + (lin - (bi * NB - (bi * (bi - 1)) / 2));

  const size_t m0 = (size_t)bi * 128, n0 = (size_t)bj * 128;

  float cur[2][2][4][4] = {};

  for (int kt = 0; kt < DFEAT; kt += 32) {
#pragma unroll
    for (int u = 0; u < 4; ++u) {
      int f = u * 256 + t;
      int r = f >> 3, c = f & 7;
      int pm = (r & 3) + 4 * ((r >> 2) ^ c);
      float4 va = *(const float4*)(F + (m0 + r) * (size_t)DFEAT + kt + 4 * c);
      As[4 * c + 0][pm] = va.x; As[4 * c + 1][pm] = va.y;
      As[4 * c + 2][pm] = va.z; As[4 * c + 3][pm] = va.w;
      float4 vb = *(const float4*)(F + (n0 + r) * (size_t)DFEAT + kt + 4 * c);
      Bs[4 * c + 0][pm] = vb.x; Bs[4 * c + 1][pm] = vb.y;
      Bs[4 * c + 2][pm] = vb.z; Bs[4 * c + 3][pm] = vb.w;
    }
    __syncthreads();
#pragma unroll 4
    for (int kk = 0; kk < 32; ++kk) {
      const int key = kk >> 2;
      float4 a0 = *(const float4*)&As[kk][4 * (tm ^ key)];
      float4 a1 = *(const float4*)&As[kk][4 * (16 + (tm ^ key))];
      float4 b0 = *(const float4*)&Bs[kk][4 * (tn ^ key)];
      float4 b1 = *(const float4*)&Bs[kk][4 * (16 + (tn ^ key))];
      float av[2][4] = {{a0.x, a0.y, a0.z, a0.w}, {a1.x, a1.y, a1.z, a1.w}};
      float bv[2][4] = {{b0.x, b0.y, b0.z, b0.w}, {b1.x, b1.y, b1.z, b1.w}};
#pragma unroll
      for (int ih = 0; ih < 2; ++ih)
#pragma unroll
        for (int jh = 0; jh < 2; ++jh)
#pragma unroll
          for (int i = 0; i < 4; ++i)
#pragma unroll
            for (int j = 0; j < 4; ++j)
              cur[ih][jh][i][j] = fmaf(av[ih][i], bv[jh][j], cur[ih][jh][i][j]);
    }
    __syncthreads();
  }

  // relu in place
#pragma unroll
  for (int ih = 0; ih < 2; ++ih)
#pragma unroll
    for (int jh = 0; jh < 2; ++jh)
#pragma unroll
      for (int i = 0; i < 4; ++i)
#pragma unroll
        for (int j = 0; j < 4; ++j)
          cur[ih][jh][i][j] = cur[ih][jh][i][j] > 0.f ? cur[ih][jh][i][j] : 0.f;

  // normal tile write (coalesced)
#pragma unroll
  for (int ih = 0; ih < 2; ++ih)
#pragma unroll
    for (int i = 0; i < 4; ++i) {
      size_t gm = m0 + 64 * ih + 4 * tm + i;
#pragma unroll
      for (int jh = 0; jh < 2; ++jh) {
        float4 res = {cur[ih][jh][i][0], cur[ih][jh][i][1],
                      cur[ih][jh][i][2], cur[ih][jh][i][3]};
        *(float4*)(C + gm * (size_t)NROW + n0 + 64 * jh + 4 * tn) = res;
      }
    }
  // mirrored tile write (skip on diagonal blocks)
  if (bi != bj) {
#pragma unroll
    for (int jh = 0; jh < 2; ++jh)
#pragma unroll
      for (int j = 0; j < 4; ++j) {
        size_t gn = n0 + 64 * jh + 4 * tn + j;
#pragma unroll
        for (int ih = 0; ih < 2; ++ih) {
          float4 res = {cur[ih][jh][0][j], cur[ih][jh][1][j],
                        cur[ih][jh][2][j], cur[ih][jh][3][j]};
          *(float4*)(C + gn * (size_t)NROW + m0 + 64 * ih + 4 * tm) = res;
        }
      }
  }
}

// ---------------- norm + fn: numpy classic pairwise (UNCHANGED, bit-critical) -----
__global__ __launch_bounds__(256) void norm_fn_kernel(const float* __restrict__ feat,
                                                      float* __restrict__ fn) {
#pragma clang fp contract(off)
  const int row = blockIdx.x * 4 + (threadIdx.x >> 6);
  const int lane = threadIdx.x & 63;
  const float* fr = feat + (size_t)row * DFEAT;
  float r = 0.f;
  if (lane < 32) {
    const float* bp = fr + (lane >> 3) * 128 + (lane & 7);
    float x = bp[0];
    r = x * x;
#pragma unroll
    for (int i = 8; i <= 120; i += 8) {
      float x2 = bp[i];
      float s = x2 * x2;
      r = r + s;
    }
  }
  float v[32];
#pragma unroll
  for (int j = 0; j < 32; ++j) v[j] = __shfl(r, j);
  float Bv[4];
#pragma unroll
  for (int b = 0; b < 4; ++b) {
    const float* p = v + 8 * b;
    Bv[b] = ((p[0] + p[1]) + (p[2] + p[3])) + ((p[4] + p[5]) + (p[6] + p[7]));
  }
  float S = (Bv[0] + Bv[1]) + (Bv[2] + Bv[3]);
  float den = (float)sqrt((double)S) + 1e-8f;
#pragma unroll
  for (int e = 0; e < 8; ++e) {
    int d = e * 64 + lane;
    fn[(size_t)row * DFEAT + d] = fr[d] / den;
  }
}

// ---------------- per-row top-32: exact byte-radix select (UNCHANGED) ----------
__device__ __forceinline__ void radix_scan(unsigned int* hist, int* st, int t) {
  if (t < 64) {
    int h0 = (int)hist[4 * t + 0], h1 = (int)hist[4 * t + 1],
        h2 = (int)hist[4 * t + 2], h3 = (int)hist[4 * t + 3];
    int S = h0 + h1 + h2 + h3;
#pragma unroll
    for (int off = 1; off < 64; off <<= 1) {
      int o = __shfl_down(S, off);
      if (t + off < 64) S += o;
    }
    int Sn = __shfl_down(S, 1);
    if (t == 63) Sn = 0;
    int needed = st[1];
    if (S >= needed && Sn < needed) {
      int cg = Sn, b;
      if (cg + h3 >= needed) b = 3;
      else if ((cg += h3) + h2 >= needed) b = 2;
      else if ((cg += h2) + h1 >= needed) b = 1;
      else { cg += h1; b = 0; }
      st[0] = (st[0] << 8) | (4 * t + b);
      st[1] = needed - cg;
    }
    if (t == 0 && S < needed) { st[2] = 1; st[1] = needed - S; }
  }
}

__global__ __launch_bounds__(256, 3) void topk_kernel(
    const float* __restrict__ sim, float* __restrict__ topv, int* __restrict__ topi)
{
  __shared__ __align__(16) unsigned int svb[NROW];  // 48 KiB: row value bits
  __shared__ unsigned int hist[256];
  __shared__ int st[4];
  __shared__ int smin[4];
  const int row = blockIdx.x, t = threadIdx.x;
  const float4* rp = (const float4*)(sim + (size_t)row * NROW);

  hist[t] = 0;
  if (t == 0) { st[0] = 0; st[1] = 32; st[2] = 0; st[3] = 0; }
  __syncthreads();

#pragma unroll
  for (int it = 0; it < 12; ++it) {
    int q = t + 256 * it;
    float4 v = rp[q];
    unsigned w0 = __float_as_uint(v.x), w1 = __float_as_uint(v.y),
             w2 = __float_as_uint(v.z), w3 = __float_as_uint(v.w);
    uint4 u; u.x = w0; u.y = w1; u.z = w2; u.w = w3;
    *(uint4*)&svb[4 * q] = u;
    if (w0) atomicAdd(&hist[w0 >> 24], 1u);
    if (w1) atomicAdd(&hist[w1 >> 24], 1u);
    if (w2) atomicAdd(&hist[w2 >> 24], 1u);
    if (w3) atomicAdd(&hist[w3 >> 24], 1u);
  }
  __syncthreads();
  radix_scan(hist, st, t);
  __syncthreads();

  for (int p = 1; p < 4; ++p) {
    if (st[2]) break;
    unsigned pref = (unsigned)st[0];
    const int sh = 24 - 8 * p;
    hist[t] = 0;
    __syncthreads();
#pragma unroll
    for (int it = 0; it < 12; ++it) {
      uint4 u = *(const uint4*)&svb[4 * (t + 256 * it)];
      unsigned ws[4] = {u.x, u.y, u.z, u.w};
#pragma unroll
      for (int e = 0; e < 4; ++e)
        if ((ws[e] >> (sh + 8)) == pref)
          atomicAdd(&hist[(ws[e] >> sh) & 255u], 1u);
    }
    __syncthreads();
    radix_scan(hist, st, t);
    __syncthreads();
  }

  const unsigned T = (unsigned)st[0];
  const int r = st[1];

#pragma unroll
  for (int it = 0; it < 12; ++it) {
    uint4 u = *(const uint4*)&svb[4 * (t + 256 * it)];
    unsigned ws[4] = {u.x, u.y, u.z, u.w};
#pragma unroll
    for (int e = 0; e < 4; ++e)
      if (ws[e] > T) {
        int pos = atomicAdd(&st[3], 1);
        topv[row * 32 + pos] = __uint_as_float(ws[e]);
        topi[row * 32 + pos] = 4 * (t + 256 * it) + e;
      }
  }

  int last = -1;
  const int base = 32 - r;
  for (int rd = 0; rd < r; ++rd) {
    int lm = 0x7fffffff;
#pragma unroll
    for (int it = 0; it < 12; ++it) {
      uint4 u = *(const uint4*)&svb[4 * (t + 256 * it)];
      unsigned ws[4] = {u.x, u.y, u.z, u.w};
#pragma unroll
      for (int e = 0; e < 4; ++e) {
        int j = 4 * (t + 256 * it) + e;
        if (ws[e] == T && j > last && j < lm) lm = j;
      }
    }
#pragma unroll
    for (int off = 32; off >= 1; off >>= 1) {
      int o = __shfl_xor(lm, off);
      if (o < lm) lm = o;
    }
    if ((t & 63) == 0) smin[t >> 6] = lm;
    __syncthreads();
    int g0 = smin[0] < smin[1] ? smin[0] : smin[1];
    int g1 = smin[2] < smin[3] ? smin[2] : smin[3];
    int g = g0 < g1 ? g0 : g1;
    if (t == 0) {
      topv[row * 32 + base + rd] = __uint_as_float(T);
      topi[row * 32 + base + rd] = g;
    }
    last = g;
    __syncthreads();
  }
}

// ---------------- zero (nontemporal: skip write-RFO fetch) + scatter ----------
__global__ __launch_bounds__(256) void zero_kernel(float* __restrict__ out) {
  size_t i = ((size_t)blockIdx.x * 256 + threadIdx.x) * 4;
  nt_float4 z = {0.f, 0.f, 0.f, 0.f};
  __builtin_nontemporal_store(z, (nt_float4*)(out + i));
}

__global__ __launch_bounds__(256) void scatter_kernel(
    const float* __restrict__ topv, const int* __restrict__ topi, float* __restrict__ out) {
  int g = blockIdx.x * 256 + threadIdx.x;
  int row = g >> 5;
  float v = 0.5f * topv[g];
  int j = topi[g];
  atomicAdd(out + (size_t)row * NROW + j, v);
  atomicAdd(out + (size_t)j * NROW + row, v);
}

// ---------------- launch ----------------
extern "C" void kernel_launch(void* const* d_in, const int* in_sizes, int n_in,
                              void* d_out, int out_size, void* d_ws, size_t ws_size,
                              hipStream_t stream)
{
  const float* X  = (const float*)d_in[0];
  const float* W1 = (const float*)d_in[1];
  const float* b1 = (const float*)d_in[2];
  const float* W2 = (const float*)d_in[3];
  const float* b2 = (const float*)d_in[4];
  const float* W3 = (const float*)d_in[5];
  const float* b3 = (const float*)d_in[6];
  float* out = (float*)d_out;

  char* ws = (char*)d_ws;
  size_t off = 0;
  auto carve = [&](size_t bytes) {
    char* p = ws + off;
    off += (bytes + 255) & ~(size_t)255;
    return (void*)p;
  };

  float* h1   = (float*)carve(4ull * NROW * HDIM);
  float* h2   = (float*)carve(4ull * NROW * HDIM);
  float* feat = (float*)carve(4ull * NROW * DFEAT);
  float* fn   = (float*)carve(4ull * NROW * DFEAT);
  float* topv = (float*)carve(4ull * NROW * 32);
  int*   topi = (int*)carve(4ull * NROW * 32);

  // MLP (chains bit-identical to round 9: K=512 single, K=1024 -> (512,512))
  gemm128<0, 1><<<dim3(HDIM / 128, NROW / 128), 256, 0, stream>>>(
      X, W1, b1, nullptr, h1, HDIM, DFEAT);
  gemm128<0, 2><<<dim3(HDIM / 128, NROW / 128), 256, 0, stream>>>(
      h1, W2, b2, nullptr, h2, HDIM, HDIM);
  gemm128<1, 2><<<dim3(DFEAT / 128, NROW / 128), 256, 0, stream>>>(
      h2, W3, b3, X, feat, DFEAT, HDIM);

  // norm + fn
  norm_fn_kernel<<<NROW / 4, 256, 0, stream>>>(feat, fn);

  // sim = relu(fn @ fn^T), symmetric: 4656 upper-tri blocks
  gemmsym<<<dim3(NB * (NB + 1) / 2), 256, 0, stream>>>(fn, out);

  // top-32 per row
  topk_kernel<<<NROW, 256, 0, stream>>>(out, topv, topi);

  // zero + symmetric scatter
  zero_kernel<<<(int)(((size_t)NROW * NROW / 4) / 256), 256, 0, stream>>>(out);
  scatter_kernel<<<(NROW * 32) / 256, 256, 0, stream>>>(topv, topi, out);
}

// Round 7
// 2825.551 us; speedup vs baseline: 1.1145x; 1.0027x over previous
//
#include <hip/hip_runtime.h>
#include <stdint.h>
#include <math.h>

typedef unsigned long long u64;

#define NROW 12288
#define DFEAT 512
#define HDIM  1024
#define NB    96   // NROW/128

// ==================================================================================
// NUMERICS CONTRACT (validated round 9, absmax 1.95e-3):
//   - every GEMM C element = single-accumulator FMA chain, k ascending, in panels
//     (512) for K=512 and (512,512) for K=1024, panels merged with one f32 add.
//     K=1024 GEMMs are TWO K=512 launches: panel-A chain stored raw to an f32
//     partial buffer (exact round-trip), panel-B computes v = part + chainB (one
//     left-assoc add), then +bias (+relu / +resid) — validated in round 5;
//   - norm = numpy classic pairwise (unchanged);
//   - top-32: exact byte-radix select (same selected SET as u64-key pop loop);
//     0.5v+0.5v symmetric scatter unchanged.
// Round 7: register-prefetch staging pipeline (issue next tile's global loads
// before the FMA phase; LDS unchanged 32KB), all GEMMs single-panel K=512,
// per-wave privatized topk histograms (4x atomic contention cut), plain zero.
// Per-element FMA chains bit-identical to round 9.
// ==================================================================================

// ---------------- GEMM: 128x128 tile, 8x8/thread, K=512, reg-prefetch ----------
// MODE 0: C = relu(acc + bias)
// MODE 2: C = acc                             (panel-A partial, raw)
// MODE 3: C = relu((part + acc) + bias)       (panel-B merge, h2)
// MODE 4: C = resid + ((part + acc) + bias)   (panel-B merge, feat)
template <int MODE>
__global__ __launch_bounds__(256, 3) void gemm128p(
    const float* __restrict__ A, const float* __restrict__ B,
    const float* __restrict__ bias, const float* __restrict__ resid,
    const float* __restrict__ part, float* __restrict__ C,
    int Nn, int lda, int ldb)
{
  __shared__ float As[32][128];   // [k][m], XOR-swizzled m-groups, no pad
  __shared__ float Bs[32][128];   // [k][n]
  const int t = threadIdx.x;
  const int tn = t & 15, tm = t >> 4;
  const size_t m0 = (size_t)blockIdx.y * 128, n0 = (size_t)blockIdx.x * 128;

  float cur[2][2][4][4] = {};     // [ih][jh][i][j]

  const float* pA = A + (m0 + (t >> 3)) * (size_t)lda + 4 * (t & 7);
  const float* pB = B + (n0 + (t >> 3)) * (size_t)ldb + 4 * (t & 7);

  float4 pva[4], pvb[4];
#pragma unroll
  for (int u = 0; u < 4; ++u) {
    pva[u] = *(const float4*)(pA + (size_t)u * 32 * lda);
    pvb[u] = *(const float4*)(pB + (size_t)u * 32 * ldb);
  }

#pragma unroll 1
  for (int kt = 0; kt < 512; kt += 32) {
#pragma unroll
    for (int u = 0; u < 4; ++u) {
      int r_ = u * 32 + (t >> 3), c_ = t & 7;
      int pm = (r_ & 3) + 4 * ((r_ >> 2) ^ c_);   // swizzled slot (bijective per row)
      As[4 * c_ + 0][pm] = pva[u].x; As[4 * c_ + 1][pm] = pva[u].y;
      As[4 * c_ + 2][pm] = pva[u].z; As[4 * c_ + 3][pm] = pva[u].w;
      Bs[4 * c_ + 0][pm] = pvb[u].x; Bs[4 * c_ + 1][pm] = pvb[u].y;
      Bs[4 * c_ + 2][pm] = pvb[u].z; Bs[4 * c_ + 3][pm] = pvb[u].w;
    }
    __syncthreads();
    if (kt + 32 < 512) {    // prefetch next tile; latency hides under FMA phase
#pragma unroll
      for (int u = 0; u < 4; ++u) {
        pva[u] = *(const float4*)(pA + (size_t)u * 32 * lda + kt + 32);
        pvb[u] = *(const float4*)(pB + (size_t)u * 32 * ldb + kt + 32);
      }
    }
#pragma unroll 4
    for (int kk = 0; kk < 32; ++kk) {
      const int key = kk >> 2;
      float4 a0 = *(const float4*)&As[kk][4 * (tm ^ key)];
      float4 a1 = *(const float4*)&As[kk][4 * (16 + (tm ^ key))];
      float4 b0 = *(const float4*)&Bs[kk][4 * (tn ^ key)];
      float4 b1 = *(const float4*)&Bs[kk][4 * (16 + (tn ^ key))];
      float av[2][4] = {{a0.x, a0.y, a0.z, a0.w}, {a1.x, a1.y, a1.z, a1.w}};
      float bv[2][4] = {{b0.x, b0.y, b0.z, b0.w}, {b1.x, b1.y, b1.z, b1.w}};
#pragma unroll
      for (int ih = 0; ih < 2; ++ih)
#pragma unroll
        for (int jh = 0; jh < 2; ++jh)
#pragma unroll
          for (int i = 0; i < 4; ++i)
#pragma unroll
            for (int j = 0; j < 4; ++j)
              cur[ih][jh][i][j] = fmaf(av[ih][i], bv[jh][j], cur[ih][jh][i][j]);
    }
    __syncthreads();
  }

#pragma unroll
  for (int ih = 0; ih < 2; ++ih)
#pragma unroll
    for (int i = 0; i < 4; ++i) {
      size_t gm = m0 + 64 * ih + 4 * tm + i;
#pragma unroll
      for (int jh = 0; jh < 2; ++jh) {
        size_t gn = n0 + 64 * jh + 4 * tn;
        float pj[4] = {0.f, 0.f, 0.f, 0.f};
        if (MODE == 3 || MODE == 4) {
          float4 pv = *(const float4*)(part + gm * (size_t)Nn + gn);
          pj[0] = pv.x; pj[1] = pv.y; pj[2] = pv.z; pj[3] = pv.w;
        }
        float rj[4] = {0.f, 0.f, 0.f, 0.f};
        if (MODE == 4) {
          float4 rv4 = *(const float4*)(resid + gm * (size_t)Nn + gn);
          rj[0] = rv4.x; rj[1] = rv4.y; rj[2] = rv4.z; rj[3] = rv4.w;
        }
        float rv[4];
#pragma unroll
        for (int j = 0; j < 4; ++j) {
          float v = cur[ih][jh][i][j];
          if (MODE == 3 || MODE == 4) v = pj[j] + v;   // panel merge: one f32 add
          if (MODE != 2) v = v + bias[gn + j];
          if (MODE == 0 || MODE == 3) v = v > 0.f ? v : 0.f;
          if (MODE == 4) v = rj[j] + v;
          rv[j] = v;
        }
        float4 res = {rv[0], rv[1], rv[2], rv[3]};
        *(float4*)(C + gm * (size_t)Nn + gn) = res;
      }
    }
}

// ---------------- symmetric sim GEMM: upper-tri blocks, reg-prefetch -------------
__global__ __launch_bounds__(256, 3) void gemmsym(
    const float* __restrict__ F, float* __restrict__ C)
{
  __shared__ float As[32][128];
  __shared__ float Bs[32][128];
  const int t = threadIdx.x;
  const int tn = t & 15, tm = t >> 4;

  // decode linear block -> (bi, bj), bi<=bj; S(b) = b*NB - b*(b-1)/2
  int lin = blockIdx.x;
  int bi = (int)(NB + 0.5 - sqrt((NB + 0.5) * (NB + 0.5) - 2.0 * (double)lin));
  if (bi < 0) bi = 0;
  if (bi > NB - 1) bi = NB - 1;
  while (bi + 1 <= NB - 1 && (bi + 1) * NB - ((bi + 1) * bi) / 2 <= lin) ++bi;
  while (bi * NB - (bi * (bi - 1)) / 2 > lin) --bi;
  int bj = bi + (lin - (bi * NB - (bi * (bi - 1)) / 2));

  const size_t m0 = (size_t)bi * 128, n0 = (size_t)bj * 128;

  float cur[2][2][4][4] = {};

  const float* pA = F + (m0 + (t >> 3)) * (size_t)DFEAT + 4 * (t & 7);
  const float* pB = F + (n0 + (t >> 3)) * (size_t)DFEAT + 4 * (t & 7);

  float4 pva[4], pvb[4];
#pragma unroll
  for (int u = 0; u < 4; ++u) {
    pva[u] = *(const float4*)(pA + (size_t)u * 32 * DFEAT);
    pvb[u] = *(const float4*)(pB + (size_t)u * 32 * DFEAT);
  }

#pragma unroll 1
  for (int kt = 0; kt < DFEAT; kt += 32) {
#pragma unroll
    for (int u = 0; u < 4; ++u) {
      int r_ = u * 32 + (t >> 3), c_ = t & 7;
      int pm = (r_ & 3) + 4 * ((r_ >> 2) ^ c_);
      As[4 * c_ + 0][pm] = pva[u].x; As[4 * c_ + 1][pm] = pva[u].y;
      As[4 * c_ + 2][pm] = pva[u].z; As[4 * c_ + 3][pm] = pva[u].w;
      Bs[4 * c_ + 0][pm] = pvb[u].x; Bs[4 * c_ + 1][pm] = pvb[u].y;
      Bs[4 * c_ + 2][pm] = pvb[u].z; Bs[4 * c_ + 3][pm] = pvb[u].w;
    }
    __syncthreads();
    if (kt + 32 < DFEAT) {
#pragma unroll
      for (int u = 0; u < 4; ++u) {
        pva[u] = *(const float4*)(pA + (size_t)u * 32 * DFEAT + kt + 32);
        pvb[u] = *(const float4*)(pB + (size_t)u * 32 * DFEAT + kt + 32);
      }
    }
#pragma unroll 4
    for (int kk = 0; kk < 32; ++kk) {
      const int key = kk >> 2;
      float4 a0 = *(const float4*)&As[kk][4 * (tm ^ key)];
      float4 a1 = *(const float4*)&As[kk][4 * (16 + (tm ^ key))];
      float4 b0 = *(const float4*)&Bs[kk][4 * (tn ^ key)];
      float4 b1 = *(const float4*)&Bs[kk][4 * (16 + (tn ^ key))];
      float av[2][4] = {{a0.x, a0.y, a0.z, a0.w}, {a1.x, a1.y, a1.z, a1.w}};
      float bv[2][4] = {{b0.x, b0.y, b0.z, b0.w}, {b1.x, b1.y, b1.z, b1.w}};
#pragma unroll
      for (int ih = 0; ih < 2; ++ih)
#pragma unroll
        for (int jh = 0; jh < 2; ++jh)
#pragma unroll
          for (int i = 0; i < 4; ++i)
#pragma unroll
            for (int j = 0; j < 4; ++j)
              cur[ih][jh][i][j] = fmaf(av[ih][i], bv[jh][j], cur[ih][jh][i][j]);
    }
    __syncthreads();
  }

  // relu in place
#pragma unroll
  for (int ih = 0; ih < 2; ++ih)
#pragma unroll
    for (int jh = 0; jh < 2; ++jh)
#pragma unroll
      for (int i = 0; i < 4; ++i)
#pragma unroll
        for (int j = 0; j < 4; ++j)
          cur[ih][jh][i][j] = cur[ih][jh][i][j] > 0.f ? cur[ih][jh][i][j] : 0.f;

  // normal tile write (coalesced)
#pragma unroll
  for (int ih = 0; ih < 2; ++ih)
#pragma unroll
    for (int i = 0; i < 4; ++i) {
      size_t gm = m0 + 64 * ih + 4 * tm + i;
#pragma unroll
      for (int jh = 0; jh < 2; ++jh) {
        float4 res = {cur[ih][jh][i][0], cur[ih][jh][i][1],
                      cur[ih][jh][i][2], cur[ih][jh][i][3]};
        *(float4*)(C + gm * (size_t)NROW + n0 + 64 * jh + 4 * tn) = res;
      }
    }
  // mirrored tile write (skip on diagonal blocks)
  if (bi != bj) {
#pragma unroll
    for (int jh = 0; jh < 2; ++jh)
#pragma unroll
      for (int j = 0; j < 4; ++j) {
        size_t gn = n0 + 64 * jh + 4 * tn + j;
#pragma unroll
        for (int ih = 0; ih < 2; ++ih) {
          float4 res = {cur[ih][jh][0][j], cur[ih][jh][1][j],
                        cur[ih][jh][2][j], cur[ih][jh][3][j]};
          *(float4*)(C + gn * (size_t)NROW + m0 + 64 * ih + 4 * tm) = res;
        }
      }
  }
}

// ---------------- norm + fn: numpy classic pairwise (UNCHANGED, bit-critical) -----
__global__ __launch_bounds__(256) void norm_fn_kernel(const float* __restrict__ feat,
                                                      float* __restrict__ fn) {
#pragma clang fp contract(off)
  const int row = blockIdx.x * 4 + (threadIdx.x >> 6);
  const int lane = threadIdx.x & 63;
  const float* fr = feat + (size_t)row * DFEAT;
  float r = 0.f;
  if (lane < 32) {
    const float* bp = fr + (lane >> 3) * 128 + (lane & 7);
    float x = bp[0];
    r = x * x;
#pragma unroll
    for (int i = 8; i <= 120; i += 8) {
      float x2 = bp[i];
      float s = x2 * x2;
      r = r + s;
    }
  }
  float v[32];
#pragma unroll
  for (int j = 0; j < 32; ++j) v[j] = __shfl(r, j);
  float Bv[4];
#pragma unroll
  for (int b = 0; b < 4; ++b) {
    const float* p = v + 8 * b;
    Bv[b] = ((p[0] + p[1]) + (p[2] + p[3])) + ((p[4] + p[5]) + (p[6] + p[7]));
  }
  float S = (Bv[0] + Bv[1]) + (Bv[2] + Bv[3]);
  float den = (float)sqrt((double)S) + 1e-8f;
#pragma unroll
  for (int e = 0; e < 8; ++e) {
    int d = e * 64 + lane;
    fn[(size_t)row * DFEAT + d] = fr[d] / den;
  }
}

// ---------------- per-row top-32: exact byte-radix select --------------------
// Per-wave privatized histograms: values concentrate in few bins (cosine sims),
// so a single shared histogram serializes same-address LDS atomics across all
// 256 threads; 4 per-wave copies cut that 4x. Merged in radix_scan.
__device__ __forceinline__ void radix_scan(const unsigned int (*h4)[256], int* st, int t) {
  if (t < 64) {
    int h0 = (int)(h4[0][4 * t + 0] + h4[1][4 * t + 0] + h4[2][4 * t + 0] + h4[3][4 * t + 0]);
    int h1 = (int)(h4[0][4 * t + 1] + h4[1][4 * t + 1] + h4[2][4 * t + 1] + h4[3][4 * t + 1]);
    int h2 = (int)(h4[0][4 * t + 2] + h4[1][4 * t + 2] + h4[2][4 * t + 2] + h4[3][4 * t + 2]);
    int h3 = (int)(h4[0][4 * t + 3] + h4[1][4 * t + 3] + h4[2][4 * t + 3] + h4[3][4 * t + 3]);
    int S = h0 + h1 + h2 + h3;
#pragma unroll
    for (int off = 1; off < 64; off <<= 1) {
      int o = __shfl_down(S, off);
      if (t + off < 64) S += o;
    }
    int Sn = __shfl_down(S, 1);
    if (t == 63) Sn = 0;
    int needed = st[1];
    if (S >= needed && Sn < needed) {
      int cg = Sn, b;
      if (cg + h3 >= needed) b = 3;
      else if ((cg += h3) + h2 >= needed) b = 2;
      else if ((cg += h2) + h1 >= needed) b = 1;
      else { cg += h1; b = 0; }
      st[0] = (st[0] << 8) | (4 * t + b);
      st[1] = needed - cg;
    }
    if (t == 0 && S < needed) { st[2] = 1; st[1] = needed - S; }
  }
}

__global__ __launch_bounds__(256, 3) void topk_kernel(
    const float* __restrict__ sim, float* __restrict__ topv, int* __restrict__ topi)
{
  __shared__ __align__(16) unsigned int svb[NROW];  // 48 KiB: row value bits
  __shared__ unsigned int hist4[4][256];            // per-wave histograms
  __shared__ int st[4];
  __shared__ int smin[4];
  const int row = blockIdx.x, t = threadIdx.x;
  const float4* rp = (const float4*)(sim + (size_t)row * NROW);
  unsigned int* myh = hist4[t >> 6];

#pragma unroll
  for (int w = 0; w < 4; ++w) hist4[w][t] = 0;
  if (t == 0) { st[0] = 0; st[1] = 32; st[2] = 0; st[3] = 0; }
  __syncthreads();

#pragma unroll
  for (int it = 0; it < 12; ++it) {
    int q = t + 256 * it;
    float4 v = rp[q];
    unsigned w0 = __float_as_uint(v.x), w1 = __float_as_uint(v.y),
             w2 = __float_as_uint(v.z), w3 = __float_as_uint(v.w);
    uint4 u; u.x = w0; u.y = w1; u.z = w2; u.w = w3;
    *(uint4*)&svb[4 * q] = u;
    if (w0) atomicAdd(&myh[w0 >> 24], 1u);
    if (w1) atomicAdd(&myh[w1 >> 24], 1u);
    if (w2) atomicAdd(&myh[w2 >> 24], 1u);
    if (w3) atomicAdd(&myh[w3 >> 24], 1u);
  }
  __syncthreads();
  radix_scan(hist4, st, t);
  __syncthreads();

  for (int p = 1; p < 4; ++p) {
    if (st[2]) break;
    unsigned pref = (unsigned)st[0];
    const int sh = 24 - 8 * p;
#pragma unroll
    for (int w = 0; w < 4; ++w) hist4[w][t] = 0;
    __syncthreads();
#pragma unroll
    for (int it = 0; it < 12; ++it) {
      uint4 u = *(const uint4*)&svb[4 * (t + 256 * it)];
      unsigned ws[4] = {u.x, u.y, u.z, u.w};
#pragma unroll
      for (int e = 0; e < 4; ++e)
        if ((ws[e] >> (sh + 8)) == pref)
          atomicAdd(&myh[(ws[e] >> sh) & 255u], 1u);
    }
    __syncthreads();
    radix_scan(hist4, st, t);
    __syncthreads();
  }

  const unsigned T = (unsigned)st[0];
  const int r = st[1];

#pragma unroll
  for (int it = 0; it < 12; ++it) {
    uint4 u = *(const uint4*)&svb[4 * (t + 256 * it)];
    unsigned ws[4] = {u.x, u.y, u.z, u.w};
#pragma unroll
    for (int e = 0; e < 4; ++e)
      if (ws[e] > T) {
        int pos = atomicAdd(&st[3], 1);
        topv[row * 32 + pos] = __uint_as_float(ws[e]);
        topi[row * 32 + pos] = 4 * (t + 256 * it) + e;
      }
  }

  int last = -1;
  const int base = 32 - r;
  for (int rd = 0; rd < r; ++rd) {
    int lm = 0x7fffffff;
#pragma unroll
    for (int it = 0; it < 12; ++it) {
      uint4 u = *(const uint4*)&svb[4 * (t + 256 * it)];
      unsigned ws[4] = {u.x, u.y, u.z, u.w};
#pragma unroll
      for (int e = 0; e < 4; ++e) {
        int j = 4 * (t + 256 * it) + e;
        if (ws[e] == T && j > last && j < lm) lm = j;
      }
    }
#pragma unroll
    for (int off = 32; off >= 1; off >>= 1) {
      int o = __shfl_xor(lm, off);
      if (o < lm) lm = o;
    }
    if ((t & 63) == 0) smin[t >> 6] = lm;
    __syncthreads();
    int g0 = smin[0] < smin[1] ? smin[0] : smin[1];
    int g1 = smin[2] < smin[3] ? smin[2] : smin[3];
    int g = g0 < g1 ? g0 : g1;
    if (t == 0) {
      topv[row * 32 + base + rd] = __uint_as_float(T);
      topi[row * 32 + base + rd] = g;
    }
    last = g;
    __syncthreads();
  }
}

// ---------------- zero + scatter ----------------
__global__ __launch_bounds__(256) void zero_kernel(float4* __restrict__ out) {
  size_t i = (size_t)blockIdx.x * 256 + threadIdx.x;
  out[i] = make_float4(0.f, 0.f, 0.f, 0.f);
}

__global__ __launch_bounds__(256) void scatter_kernel(
    const float* __restrict__ topv, const int* __restrict__ topi, float* __restrict__ out) {
  int g = blockIdx.x * 256 + threadIdx.x;
  int row = g >> 5;
  float v = 0.5f * topv[g];
  int j = topi[g];
  atomicAdd(out + (size_t)row * NROW + j, v);
  atomicAdd(out + (size_t)j * NROW + row, v);
}

// ---------------- launch ----------------
extern "C" void kernel_launch(void* const* d_in, const int* in_sizes, int n_in,
                              void* d_out, int out_size, void* d_ws, size_t ws_size,
                              hipStream_t stream)
{
  const float* X  = (const float*)d_in[0];
  const float* W1 = (const float*)d_in[1];
  const float* b1 = (const float*)d_in[2];
  const float* W2 = (const float*)d_in[3];
  const float* b2 = (const float*)d_in[4];
  const float* W3 = (const float*)d_in[5];
  const float* b3 = (const float*)d_in[6];
  float* out = (float*)d_out;

  char* ws = (char*)d_ws;
  size_t off = 0;
  auto carve = [&](size_t bytes) {
    char* p = ws + off;
    off += (bytes + 255) & ~(size_t)255;
    return (void*)p;
  };

  float* h1   = (float*)carve(4ull * NROW * HDIM);
  float* h2   = (float*)carve(4ull * NROW * HDIM);
  float* feat = (float*)carve(4ull * NROW * DFEAT);
  float* fn   = (float*)carve(4ull * NROW * DFEAT);
  float* topv = (float*)carve(4ull * NROW * 32);
  int*   topi = (int*)carve(4ull * NROW * 32);

  // Partial buffers alias currently-dead regions:
  //  P2 (12288x1024, 50MB) = feat+fn (contiguous carves, both free during MLP)
  //  P3 (12288x512, 25MB)  = fn
  float* P2 = feat;
  float* P3 = fn;

  // W1: K=512 single chain
  gemm128p<0><<<dim3(HDIM / 128, NROW / 128), 256, 0, stream>>>(
      X, W1, b1, nullptr, nullptr, h1, HDIM, DFEAT, DFEAT);
  // W2: K=1024 as (512,512) panels merged with one add
  gemm128p<2><<<dim3(HDIM / 128, NROW / 128), 256, 0, stream>>>(
      h1, W2, nullptr, nullptr, nullptr, P2, HDIM, HDIM, HDIM);
  gemm128p<3><<<dim3(HDIM / 128, NROW / 128), 256, 0, stream>>>(
      h1 + 512, W2 + 512, b2, nullptr, P2, h2, HDIM, HDIM, HDIM);
  // W3: K=1024 as (512,512) panels, + resid
  gemm128p<2><<<dim3(DFEAT / 128, NROW / 128), 256, 0, stream>>>(
      h2, W3, nullptr, nullptr, nullptr, P3, DFEAT, HDIM, HDIM);
  gemm128p<4><<<dim3(DFEAT / 128, NROW / 128), 256, 0, stream>>>(
      h2 + 512, W3 + 512, b3, X, P3, feat, DFEAT, HDIM, HDIM);

  // norm + fn (overwrites P3 region — P3 dead by now)
  norm_fn_kernel<<<NROW / 4, 256, 0, stream>>>(feat, fn);

  // sim = relu(fn @ fn^T), symmetric: 4656 upper-tri blocks
  gemmsym<<<dim3(NB * (NB + 1) / 2), 256, 0, stream>>>(fn, out);

  // top-32 per row
  topk_kernel<<<NROW, 256, 0, stream>>>(out, topv, topi);

  // zero + symmetric scatter
  zero_kernel<<<(int)(((size_t)NROW * NROW / 4) / 256), 256, 0, stream>>>((float4*)out);
  scatter_kernel<<<(NROW * 32) / 256, 256, 0, stream>>>(topv, topi, out);
}